// Round 9
// baseline (348.238 us; speedup 1.0000x reference)
//
#include <hip/hip_runtime.h>
#include <hip/hip_bf16.h>
#include <math.h>

typedef __bf16 bf16_t;
typedef __bf16 bf16x8 __attribute__((ext_vector_type(8)));
typedef __bf16 bf16x4 __attribute__((ext_vector_type(4)));
typedef float f32x4 __attribute__((ext_vector_type(4)));

#define AS1q __attribute__((address_space(1)))
#define AS3q __attribute__((address_space(3)))

__device__ __forceinline__ void gload_lds16(const bf16_t* g, bf16_t* l) {
    __builtin_amdgcn_global_load_lds((AS1q void*)g, (AS3q void*)l, 16, 0, 0);
}

// ------------------------------------------------------------------
// constants (B=1, H=W=T=48, C=96, nh=3, hd=32)
// ------------------------------------------------------------------
#define LROWS   110592
#define CDIM    96
#define NTOK    2304
#define FDIM    1536
#define YSTR    3538944ll     // 2304*1536
#define SSTR    5308416ll     // 2304*2304
#define SCALE_Q 0.1767766952966369f

// ------------------------------------------------------------------
// exact-erf GELU, branch-free (A&S 7.1.26, |erf err| <= 1.5e-7)
// ------------------------------------------------------------------
__device__ __forceinline__ float gelu_f(float v) {
    float xs = v * 0.70710678118654752f;
    float a  = fabsf(xs);
    float t  = __builtin_amdgcn_rcpf(fmaf(0.3275911f, a, 1.0f));
    float p  = t * fmaf(t, fmaf(t, fmaf(t, fmaf(t, 1.061405429f, -1.453152027f),
                                        1.421413741f), -0.284496736f), 0.254829592f);
    float e  = __expf(-a * a);
    float erfx = copysignf(fmaf(-p, e, 1.0f), xs);
    return 0.5f * v * (1.0f + erfx);
}

// ------------------------------------------------------------------
// weight fp32 -> bf16
// ------------------------------------------------------------------
__global__ __launch_bounds__(256)
void conv_w(const float* __restrict__ a, const float* __restrict__ b,
            const float* __restrict__ c, const float* __restrict__ d,
            bf16_t* __restrict__ out)
{
    int i = blockIdx.x * 256 + threadIdx.x;
    float v;
    if (i < 27648)       v = a[i];
    else if (i < 36864)  v = b[i - 27648];
    else if (i < 73728)  v = c[i - 36864];
    else                 v = d[i - 73728];
    out[i] = (bf16_t)v;
}

// ------------------------------------------------------------------
// row softmax over 2304, S bf16 -> P bf16.  One WAVE per row (no LDS).
// ------------------------------------------------------------------
__global__ __launch_bounds__(256)
void softmax_k(const bf16_t* __restrict__ S, bf16_t* __restrict__ P,
               long long sZ, long long pZ)
{
    int wv = threadIdx.x >> 6, lane = threadIdx.x & 63;
    int row = blockIdx.x * 4 + wv;
    const bf16_t* sr = S + (size_t)blockIdx.z * sZ + (size_t)row * NTOK;
    bf16_t* pr = P + (size_t)blockIdx.z * pZ + (size_t)row * NTOK;
    float v[36];
    float mx = -1e30f;
    #pragma unroll
    for (int t = 0; t < 9; t++) {
        bf16x4 c = *(const bf16x4*)(sr + (size_t)(t * 64 + lane) * 4);
        #pragma unroll
        for (int j = 0; j < 4; j++) { v[t*4+j] = (float)c[j]; mx = fmaxf(mx, v[t*4+j]); }
    }
    #pragma unroll
    for (int off = 32; off > 0; off >>= 1) mx = fmaxf(mx, __shfl_xor(mx, off, 64));
    float sum = 0.f;
    #pragma unroll
    for (int j = 0; j < 36; j++) { v[j] = __expf(v[j] - mx); sum += v[j]; }
    #pragma unroll
    for (int off = 32; off > 0; off >>= 1) sum += __shfl_xor(sum, off, 64);
    float inv = 1.f / sum;
    #pragma unroll
    for (int t = 0; t < 9; t++) {
        bf16x4 o;
        #pragma unroll
        for (int j = 0; j < 4; j++) o[j] = (bf16_t)(v[t*4+j] * inv);
        *(bf16x4*)(pr + (size_t)(t * 64 + lane) * 4) = o;
    }
}

// ------------------------------------------------------------------
// bf16 MFMA GEMM v5 (attention), 8-PHASE 256x256 (T3+T4 per m201):
// C[M,N] = A[M,K] @ W[N,K]^T.  512 thr = 8 waves (2M x 4N), BK=64,
// LDS 128KB: per buffer 2 A-halves (rows 0..127/128..255) + 2
// B-halves, each [128][64] XOR-swizzled (proven 0-conflict scheme).
// 4 phases per K-tile t, each {ds_read subtile -> barrier ->
// lgkmcnt(0) -> 16 MFMA -> barrier}; quadrant order (rh,ch) =
// (0,0),(0,1),(1,1),(1,0) so only one operand reloads per phase.
// Staging: p0 -> B-halves(t+1) into buf^1 (slots last read (t-1)p3,
// fenced); p3 -> A-halves(t+2) into buf (slots last read t-p2).
// ONE counted vmcnt per K-tile, BEFORE the tile-end barrier:
//   steady ledger: after tile-end vmcnt(4) the 4 outstanding loads
//   are exactly A(t+2); +4 B(t+1)@p0, +4 A(t+2)@p3 -> 12 -> vmcnt(4)
//   drains {A(t+1),B(t+1)} = precisely what tile t+1 reads. Every
//   wave drains ITS OWN loads, then the barrier publishes to all.
// Prologue: stage A(0),B(0),A(1) = 12 loads, vmcnt(4), barrier.
// Tail: vmcnt(0) at end of tile nt-2; stage guards t+1<nt / t+2<nt.
// R4 failed as ONE coarse phase/K-tile (m196's negative variant);
// this is the fine interleave that makes T3+T4 pay (m218: +38-73%).
// EPI: 1=S bf16 (*scale)   2=PV scatter (o_rows)
// ------------------------------------------------------------------
template<int EPI>
__global__ __launch_bounds__(512, 1)
void gemm_bt8(const bf16_t* __restrict__ A, const bf16_t* __restrict__ W,
              void* __restrict__ out, int K,
              long long aZ, long long wZ, long long oZ, float scale)
{
    constexpr int BK = 64;
    __shared__ __attribute__((aligned(16))) bf16_t LA[2][2][128 * 64];
    __shared__ __attribute__((aligned(16))) bf16_t LB[2][2][128 * 64];

    // bijective XCD chunk swizzle (m204)
    const int nb = gridDim.x;
    const int orig = blockIdx.x;
    const int q8 = nb >> 3, r8 = nb & 7;
    const int xcd = orig & 7;
    const int wgid = (xcd < r8 ? xcd * (q8 + 1) : r8 * (q8 + 1) + (xcd - r8) * q8)
                   + (orig >> 3);
    const int bx = wgid % 9;          // M = 2304 -> 9 row-blocks
    const int by = wgid / 9;

    const int tid = threadIdx.x;
    const int wave = tid >> 6, lane = tid & 63;
    const int quad = lane >> 4, l16 = lane & 15;
    const int wm = wave >> 2, wn = wave & 3;     // 2 x 4 wave grid
    const int z = blockIdx.z;
    A += (size_t)z * aZ;
    W += (size_t)z * wZ;
    const int m0 = bx * 256, n0 = by * 256;

    f32x4 acc[8][4];
    #pragma unroll
    for (int i = 0; i < 8; i++)
        #pragma unroll
        for (int j = 0; j < 4; j++) { f32x4 zz = {0.f, 0.f, 0.f, 0.f}; acc[i][j] = zz; }

    const int srow = lane >> 3;
    const int scol = lane & 7;

    auto stageA = [&](int buf, int h, int kt) {
        #pragma unroll
        for (int s = 0; s < 2; s++) {
            int it = s * 8 + wave;
            int r = it * 8 + srow;
            int cg = scol ^ (r & 7);
            gload_lds16(A + (size_t)(m0 + h * 128 + r) * K + kt * BK + cg * 8,
                        &LA[buf][h][it * 512]);
        }
    };
    auto stageB = [&](int buf, int h, int kt) {
        #pragma unroll
        for (int s = 0; s < 2; s++) {
            int it = s * 8 + wave;
            int r = it * 8 + srow;
            int cg = scol ^ (r & 7);
            gload_lds16(W + (size_t)(n0 + h * 128 + r) * K + kt * BK + cg * 8,
                        &LB[buf][h][it * 512]);
        }
    };

    const int bslot = wn >> 1, bcol0 = (wn & 1) * 64;
    bf16x8 afr[4][2], bfr[2][2];

    auto ldA = [&](int buf, int rh) {
        #pragma unroll
        for (int i = 0; i < 4; i++) {
            int lr = rh * 64 + i * 16 + l16;
            #pragma unroll
            for (int kk = 0; kk < 2; kk++)
                afr[i][kk] = *(const bf16x8*)&LA[buf][wm][lr * 64 + (((kk * 4 + quad) ^ (lr & 7)) << 3)];
        }
    };
    auto ldB = [&](int buf, int ch) {
        #pragma unroll
        for (int j = 0; j < 2; j++) {
            int lc = bcol0 + ch * 32 + j * 16 + l16;
            #pragma unroll
            for (int kk = 0; kk < 2; kk++)
                bfr[j][kk] = *(const bf16x8*)&LB[buf][bslot][lc * 64 + (((kk * 4 + quad) ^ (lc & 7)) << 3)];
        }
    };
    auto mfma16 = [&](int rh, int ch) {
        asm volatile("s_waitcnt lgkmcnt(0)" ::: "memory");
        __builtin_amdgcn_sched_barrier(0);
        __builtin_amdgcn_s_setprio(1);
        #pragma unroll
        for (int kk = 0; kk < 2; kk++)
            #pragma unroll
            for (int i = 0; i < 4; i++)
                #pragma unroll
                for (int j = 0; j < 2; j++)
                    acc[rh * 4 + i][ch * 2 + j] = __builtin_amdgcn_mfma_f32_16x16x32_bf16(
                        afr[i][kk], bfr[j][kk], acc[rh * 4 + i][ch * 2 + j], 0, 0, 0);
        __builtin_amdgcn_s_setprio(0);
    };
    auto bar = [&] {
        __builtin_amdgcn_sched_barrier(0);
        __builtin_amdgcn_s_barrier();
        __builtin_amdgcn_sched_barrier(0);
    };

    const int nt = K / BK;

    // prologue: A(0), B(0), A(1) = 12 loads; keep newest 4 (= A(1))
    stageA(0, 0, 0); stageA(0, 1, 0);
    stageB(0, 0, 0); stageB(0, 1, 0);
    stageA(1, 0, 1); stageA(1, 1, 1);
    asm volatile("s_waitcnt vmcnt(4)" ::: "memory");
    bar();

    for (int t = 0; t < nt; t++) {
        const int cb = t & 1;
        // ---- p0: quadrant (0,0) ----
        ldA(cb, 0); ldB(cb, 0);
        if (t + 1 < nt) { stageB(cb ^ 1, 0, t + 1); stageB(cb ^ 1, 1, t + 1); }
        bar();
        mfma16(0, 0);
        bar();
        // ---- p1: quadrant (0,1) ----
        ldB(cb, 1);
        bar();
        mfma16(0, 1);
        bar();
        // ---- p2: quadrant (1,1) ----
        ldA(cb, 1);
        bar();
        mfma16(1, 1);
        bar();
        // ---- p3: quadrant (1,0) ----
        ldB(cb, 0);
        if (t + 2 < nt) { stageA(cb, 0, t + 2); stageA(cb, 1, t + 2); }
        bar();
        mfma16(1, 0);
        // tile-end: drain next tile's loads BEFORE the barrier so the
        // barrier publishes them to all waves (counted, never 0 mid-loop)
        if (t < nt - 1) {
            if (t == nt - 2) asm volatile("s_waitcnt vmcnt(0)" ::: "memory");
            else             asm volatile("s_waitcnt vmcnt(4)" ::: "memory");
        }
        bar();
    }

    #pragma unroll
    for (int i = 0; i < 8; i++)
        #pragma unroll
        for (int j = 0; j < 4; j++)
            #pragma unroll
            for (int ri = 0; ri < 4; ri++) {
                int r = m0 + wm * 128 + i * 16 + quad * 4 + ri;
                int c = n0 + wn * 64 + j * 16 + l16;
                float v = acc[i][j][ri];
                if constexpr (EPI == 1) {
                    bf16_t* op = (bf16_t*)out + (size_t)z * oZ;
                    op[(size_t)r * NTOK + c] = (bf16_t)(v * scale);
                } else {
                    int b = r / 48, rr = r - b * 48;
                    ((bf16_t*)out)[((size_t)(b * NTOK + rr * 48 + z * 16)) * CDIM + c] = (bf16_t)v;
                }
            }
}

// ------------------------------------------------------------------
// QKV GEMM with FUSED LN1 + axial permute (R8-proven, -22us):
// C[M,288] = LN1(x)[M,96] @ Wqkv^T, A-rows computed inline.
// ------------------------------------------------------------------
__global__ __launch_bounds__(256, 2)
void qkv_fused(const float* __restrict__ X, const bf16_t* __restrict__ Wg,
               bf16_t* __restrict__ out, const float* __restrict__ bias,
               bf16_t* __restrict__ outv,
               const float* __restrict__ g1, const float* __restrict__ b1)
{
    constexpr int N = 288, K = 96;
    constexpr int KP = K + 8;
    constexpr int NT = N / 16;
    constexpr int KI = K / 32;     // 3
    __shared__ __attribute__((aligned(16))) bf16_t Ws[N * KP];

    const int tid = threadIdx.x;
    const int wave = tid >> 6, lane = tid & 63;
    const int quad = lane >> 4, l16 = lane & 15;
    const int m0 = blockIdx.x * 256;

    constexpr int CH = N * K / 8;
    for (int c = tid; c < CH; c += 256) {
        int row = c / (K / 8), kc = c - row * (K / 8);
        bf16x8 w = *(const bf16x8*)(Wg + row * K + kc * 8);
        *(bf16x8*)(Ws + row * KP + kc * 8) = w;
    }
    __syncthreads();

    const int t = m0 / NTOK;
    const int nb = m0 - t * NTOK;

    // per-lane gamma/beta for cols quad*8 + kk*32 + (0..7)
    f32x4 gv[KI][2], bv[KI][2];
    #pragma unroll
    for (int kk = 0; kk < KI; kk++) {
        const float* gp = g1 + quad * 8 + kk * 32;
        const float* bp = b1 + quad * 8 + kk * 32;
        gv[kk][0] = *(const f32x4*)gp;     gv[kk][1] = *(const f32x4*)(gp + 4);
        bv[kk][0] = *(const f32x4*)bp;     bv[kk][1] = *(const f32x4*)(bp + 4);
    }

    // A fragments with inline LN (row l = (nb+wave*64+l16+i*16)*48 + t)
    bf16x8 af[4][KI];
    #pragma unroll
    for (int i = 0; i < 4; i++) {
        size_t l = (size_t)(nb + wave * 64 + l16 + i * 16) * 48 + t;
        const float* xr = X + l * 96 + quad * 8;
        f32x4 xv[KI][2];
        float s1 = 0.f, s2 = 0.f;
        #pragma unroll
        for (int kk = 0; kk < KI; kk++) {
            xv[kk][0] = *(const f32x4*)(xr + kk * 32);
            xv[kk][1] = *(const f32x4*)(xr + kk * 32 + 4);
            #pragma unroll
            for (int h = 0; h < 2; h++)
                #pragma unroll
                for (int j = 0; j < 4; j++) {
                    float v = xv[kk][h][j];
                    s1 += v; s2 += v * v;
                }
        }
        // cross-quad reduce (lanes l16, +16, +32, +48 share the row)
        s1 += __shfl_xor(s1, 16, 64);  s1 += __shfl_xor(s1, 32, 64);
        s2 += __shfl_xor(s2, 16, 64);  s2 += __shfl_xor(s2, 32, 64);
        float mean = s1 * (1.f / 96.f);
        float var  = s2 * (1.f / 96.f) - mean * mean;
        float rstd = rsqrtf(var + 1e-5f);
        #pragma unroll
        for (int kk = 0; kk < KI; kk++)
            #pragma unroll
            for (int h = 0; h < 2; h++)
                #pragma unroll
                for (int j = 0; j < 4; j++)
                    af[i][kk][h * 4 + j] =
                        (bf16_t)((xv[kk][h][j] - mean) * rstd * gv[kk][h][j] + bv[kk][h][j]);
    }

    #pragma unroll 2
    for (int nt = 0; nt < NT; nt++) {
        bf16x8 bfr[KI];
        #pragma unroll
        for (int kk = 0; kk < KI; kk++)
            bfr[kk] = *(const bf16x8*)(Ws + (nt * 16 + l16) * KP + kk * 32 + quad * 8);
        f32x4 a4[4];
        #pragma unroll
        for (int i = 0; i < 4; i++) { f32x4 zz = {0.f, 0.f, 0.f, 0.f}; a4[i] = zz; }
        #pragma unroll
        for (int kk = 0; kk < KI; kk++)
            #pragma unroll
            for (int i = 0; i < 4; i++)
                a4[i] = __builtin_amdgcn_mfma_f32_16x16x32_bf16(af[i][kk], bfr[kk], a4[i], 0, 0, 0);

        int c = nt * 16 + l16;
        int jj = t * 288 + c;
        int g = jj / FDIM, mm = jj - g * FDIM;
        float bvv = bias[c];
        if (g < 6) {
            bf16_t* yp = out + (size_t)g * YSTR + mm;
            #pragma unroll
            for (int i = 0; i < 4; i++)
                #pragma unroll
                for (int ri = 0; ri < 4; ri++) {
                    int n = nb + wave * 64 + i * 16 + quad * 4 + ri;
                    yp[(size_t)n * FDIM] = (bf16_t)(a4[i][ri] + bvv);
                }
        } else {
            bf16_t* vp = outv + (size_t)(g - 6) * YSTR + (size_t)mm * NTOK;
            #pragma unroll
            for (int i = 0; i < 4; i++) {
                int n0q = nb + wave * 64 + i * 16 + quad * 4;
                bf16x4 o;
                #pragma unroll
                for (int ri = 0; ri < 4; ri++) o[ri] = (bf16_t)(a4[i][ri] + bvv);
                *(bf16x4*)(vp + n0q) = o;
            }
        }
    }
}

// ------------------------------------------------------------------
// Weight-resident GEMM (proj path):  C[M,N] = A[M,K] @ W[N,K]^T.
// EPI 5: proj+bias+residual -> out f32 AND fused LayerNorm -> out2 bf16
// ------------------------------------------------------------------
template<int N, int K, int KC, int EPI>
__global__ __launch_bounds__(256, 2)
void gemm_ws(const bf16_t* __restrict__ A, const bf16_t* __restrict__ Wg,
             void* __restrict__ out, const float* __restrict__ bias,
             const float* __restrict__ resid,
             bf16_t* __restrict__ out2, const float* __restrict__ g2,
             const float* __restrict__ b2)
{
    constexpr int KP = K + 8;
    constexpr int NT = N / 16;
    constexpr int KI = KC / 32;
    __shared__ __attribute__((aligned(16))) bf16_t Ws[N * KP];

    const int tid = threadIdx.x;
    const int wave = tid >> 6, lane = tid & 63;
    const int quad = lane >> 4, l16 = lane & 15;
    const int m0 = blockIdx.x * 256;

    constexpr int CH = N * K / 8;
    for (int c = tid; c < CH; c += 256) {
        int row = c / (K / 8), kc = c - row * (K / 8);
        bf16x8 w = *(const bf16x8*)(Wg + row * K + kc * 8);
        *(bf16x8*)(Ws + row * KP + kc * 8) = w;
    }
    __syncthreads();

    const bf16_t* Ar = A + (size_t)(m0 + wave * 64 + l16) * K + quad * 8;

    f32x4 acc[4][NT];
    #pragma unroll
    for (int i = 0; i < 4; i++)
        #pragma unroll
        for (int j = 0; j < NT; j++) { f32x4 zz = {0.f, 0.f, 0.f, 0.f}; acc[i][j] = zz; }
    for (int kc0 = 0; kc0 < K; kc0 += KC) {
        bf16x8 af[4][KI];
        #pragma unroll
        for (int i = 0; i < 4; i++)
            #pragma unroll
            for (int kk = 0; kk < KI; kk++)
                af[i][kk] = *(const bf16x8*)(Ar + (size_t)i * 16 * K + kc0 + kk * 32);
        #pragma unroll
        for (int nt = 0; nt < NT; nt++) {
            #pragma unroll
            for (int kk = 0; kk < KI; kk++) {
                bf16x8 b = *(const bf16x8*)(Ws + (nt * 16 + l16) * KP + kc0 + kk * 32 + quad * 8);
                #pragma unroll
                for (int i = 0; i < 4; i++)
                    acc[i][nt] = __builtin_amdgcn_mfma_f32_16x16x32_bf16(af[i][kk], b, acc[i][nt], 0, 0, 0);
            }
        }
    }
    if constexpr (EPI == 5) {
        float bv[NT], gv[NT], bb[NT];
        #pragma unroll
        for (int nt = 0; nt < NT; nt++) {
            int c = nt * 16 + l16;
            bv[nt] = bias[c]; gv[nt] = g2[c]; bb[nt] = b2[c];
        }
        #pragma unroll
        for (int i = 0; i < 4; i++)
            #pragma unroll
            for (int ri = 0; ri < 4; ri++) {
                int r = m0 + wave * 64 + i * 16 + quad * 4 + ri;
                float u[NT];
                float s = 0.f;
                #pragma unroll
                for (int nt = 0; nt < NT; nt++) {
                    int c = nt * 16 + l16;
                    u[nt] = acc[i][nt][ri] + bv[nt] + resid[(size_t)r * N + c];
                    ((float*)out)[(size_t)r * N + c] = u[nt];
                    s += u[nt];
                }
                #pragma unroll
                for (int off = 8; off > 0; off >>= 1) s += __shfl_xor(s, off, 64);
                float mean = s * (1.f / 96.f);
                float vs = 0.f;
                #pragma unroll
                for (int nt = 0; nt < NT; nt++) {
                    float dd = u[nt] - mean;
                    u[nt] = dd;
                    vs += dd * dd;
                }
                #pragma unroll
                for (int off = 8; off > 0; off >>= 1) vs += __shfl_xor(vs, off, 64);
                float rstd = rsqrtf(vs * (1.f / 96.f) + 1e-5f);
                #pragma unroll
                for (int nt = 0; nt < NT; nt++) {
                    int c = nt * 16 + l16;
                    out2[(size_t)r * N + c] = (bf16_t)(u[nt] * rstd * gv[nt] + bb[nt]);
                }
            }
    }
}

// ------------------------------------------------------------------
// Fused MLP v3b: out = x2 + fc2(gelu(fc1(h2)+b1))+b2  (t1 never in HBM)
// BM=128, 4 waves x 32 rows, one barrier/chunk (Tb wave-private),
// 4 blocks/CU, A&S erf GELU, conflict-free Tb stride 44 (R7).
// ------------------------------------------------------------------
__global__ __launch_bounds__(256, 4)
void mlp_fused(const bf16_t* __restrict__ A, const bf16_t* __restrict__ W1g,
               const bf16_t* __restrict__ W2g, const float* __restrict__ b1,
               const float* __restrict__ b2, const float* __restrict__ resid,
               float* __restrict__ out)
{
    constexpr int KP1 = 104;   // 96+8: B-frag rows stride 52 dwords (uniform spread)
    constexpr int TBS = 44;    // Tb row stride: 22 dw -> conflict-free
    __shared__ __attribute__((aligned(16))) bf16_t W1c[2][32 * KP1]; // 2x6656 B
    __shared__ __attribute__((aligned(16))) bf16_t W2c[2][96 * 40];  // 2x7680 B
    __shared__ __attribute__((aligned(16))) bf16_t Tb[128 * TBS];    // 11264 B

    const int tid = threadIdx.x;
    const int wave = tid >> 6, lane = tid & 63;
    const int quad = lane >> 4, l16 = lane & 15;
    const int m0 = blockIdx.x * 128;

    // A rows resident (full K=96): wave handles 32 rows (2 m-tiles)
    const bf16_t* Ar = A + (size_t)(m0 + wave * 32 + l16) * 96 + quad * 8;
    bf16x8 af[2][3];
    #pragma unroll
    for (int i = 0; i < 2; i++)
        #pragma unroll
        for (int kk = 0; kk < 3; kk++)
            af[i][kk] = *(const bf16x8*)(Ar + (size_t)i * 16 * 96 + kk * 32);

    // prefetch chunk 0 of W1 (32x96) and W2 (96 x cols 0..32) to regs
    bf16x4 w1n[3], w2n[3];
    #pragma unroll
    for (int q = 0; q < 3; q++) {
        int e = q * 256 + tid;
        w1n[q] = *(const bf16x4*)(W1g + e * 4);                       // rows 0..32 contiguous
        int row = e >> 3, sub = e & 7;
        w2n[q] = *(const bf16x4*)(W2g + row * 384 + sub * 4);
    }
    #pragma unroll
    for (int q = 0; q < 3; q++) {
        int e = q * 256 + tid;
        int r1 = e / 24, s1 = e - r1 * 24;
        *(bf16x4*)(&W1c[0][r1 * KP1 + s1 * 4]) = w1n[q];
        int row = e >> 3, sub = e & 7;
        *(bf16x4*)(&W2c[0][row * 40 + sub * 4]) = w2n[q];
    }
    __syncthreads();

    f32x4 acc2[2][6];
    #pragma unroll
    for (int i = 0; i < 2; i++)
        #pragma unroll
        for (int j = 0; j < 6; j++) { f32x4 zz = {0.f, 0.f, 0.f, 0.f}; acc2[i][j] = zz; }

    for (int c = 0; c < 12; c++) {
        const int pb = c & 1;
        // prefetch chunk c+1 to regs (vmcnt hidden by fc1 MFMAs + GELU)
        if (c < 11) {
            #pragma unroll
            for (int q = 0; q < 3; q++) {
                int e = q * 256 + tid;
                w1n[q] = *(const bf16x4*)(W1g + (c + 1) * 3072 + e * 4);
                int row = e >> 3, sub = e & 7;
                w2n[q] = *(const bf16x4*)(W2g + row * 384 + (c + 1) * 32 + sub * 4);
            }
        }
        // fc1 chunk: cols c*32..+32  (12 MFMA/wave), reads W1c[pb]
        f32x4 a1[2][2];
        #pragma unroll
        for (int i = 0; i < 2; i++)
            #pragma unroll
            for (int s = 0; s < 2; s++) { f32x4 zz = {0.f, 0.f, 0.f, 0.f}; a1[i][s] = zz; }
        #pragma unroll
        for (int s = 0; s < 2; s++) {
            int n = s * 16 + l16;
            #pragma unroll
            for (int kk = 0; kk < 3; kk++) {
                bf16x8 b = *(const bf16x8*)(&W1c[pb][n * KP1 + kk * 32 + quad * 8]);
                #pragma unroll
                for (int i = 0; i < 2; i++)
                    a1[i][s] = __builtin_amdgcn_mfma_f32_16x16x32_bf16(af[i][kk], b, a1[i][s], 0, 0, 0);
            }
        }
        // GELU -> Tb (wave-private rows; no barrier needed before fc2)
        #pragma unroll
        for (int s = 0; s < 2; s++) {
            int n = c * 32 + s * 16 + l16;
            float bv = b1[n];
            #pragma unroll
            for (int i = 0; i < 2; i++)
                #pragma unroll
                for (int ri = 0; ri < 4; ri++) {
                    float u = gelu_f(a1[i][s][ri] + bv);
                    Tb[(wave * 32 + i * 16 + quad * 4 + ri) * TBS + s * 16 + l16] = (bf16_t)u;
                }
        }
        // stage chunk c+1 into buffer pb^1 (its last readers finished
        // before barrier c-1 -> safe with the single end-of-chunk barrier)
        if (c < 11) {
            #pragma unroll
            for (int q = 0; q < 3; q++) {
                int e = q * 256 + tid;
                int r1 = e / 24, s1 = e - r1 * 24;
                *(bf16x4*)(&W1c[pb ^ 1][r1 * KP1 + s1 * 4]) = w1n[q];
                int row = e >> 3, sub = e & 7;
                *(bf16x4*)(&W2c[pb ^ 1][row * 40 + sub * 4]) = w2n[q];
            }
        }
        // fc2 partial (K=32): 12 MFMA/wave, reads own Tb rows + W2c[pb]
        bf16x8 a2[2];
        #pragma unroll
        for (int i = 0; i < 2; i++) {
            const bf16_t* tp = Tb + (wave * 32 + i * 16 + l16) * TBS + quad * 8;
            bf16x4 lo = *(const bf16x4*)tp;
            bf16x4 hi = *(const bf16x4*)(tp + 4);
            #pragma unroll
            for (int j = 0; j < 4; j++) { a2[i][j] = lo[j]; a2[i][j + 4] = hi[j]; }
        }
        #pragma unroll
        for (int nt = 0; nt < 6; nt++) {
            bf16x8 b = *(const bf16x8*)(&W2c[pb][(nt * 16 + l16) * 40 + quad * 8]);
            #pragma unroll
            for (int i = 0; i < 2; i++)
                acc2[i][nt] = __builtin_amdgcn_mfma_f32_16x16x32_bf16(a2[i], b, acc2[i][nt], 0, 0, 0);
        }
        __syncthreads();   // one barrier per chunk
    }

    // epilogue: + b2 + resid -> f32 out
    #pragma unroll
    for (int i = 0; i < 2; i++)
        #pragma unroll
        for (int nt = 0; nt < 6; nt++)
            #pragma unroll
            for (int ri = 0; ri < 4; ri++) {
                int r = m0 + wave * 32 + i * 16 + quad * 4 + ri;
                int cc = nt * 16 + l16;
                out[(size_t)r * 96 + cc] = acc2[i][nt][ri] + b2[cc] + resid[(size_t)r * 96 + cc];
            }
}

// ------------------------------------------------------------------
extern "C" void kernel_launch(void* const* d_in, const int* in_sizes, int n_in,
                              void* d_out, int out_size, void* d_ws, size_t ws_size,
                              hipStream_t stream)
{
    const float* x      = (const float*)d_in[0];
    const float* ln1_g  = (const float*)d_in[2];
    const float* ln1_b  = (const float*)d_in[3];
    const float* qkv_w  = (const float*)d_in[4];
    const float* qkv_b  = (const float*)d_in[5];
    const float* proj_w = (const float*)d_in[6];
    const float* proj_b = (const float*)d_in[7];
    const float* ln2_g  = (const float*)d_in[8];
    const float* ln2_b  = (const float*)d_in[9];
    const float* fc1_w  = (const float*)d_in[10];
    const float* fc1_b  = (const float*)d_in[11];
    const float* fc2_w  = (const float*)d_in[12];
    const float* fc2_b  = (const float*)d_in[13];

    // ---- workspace 170.1 MB (aliased by liveness) ----
    const size_t SZ_WB = 110592ull * 2;
    const size_t SZ_HP = 10616832ull * 2;
    const size_t SZ_Y  = 31850496ull * 2;
    const size_t SZ_YV = 10616832ull * 2;

    char* ws = (char*)d_ws;
    size_t oWB = 0;
    size_t oHP = oWB + SZ_WB;
    size_t oY  = oHP + SZ_HP;
    size_t oYV = oY + SZ_Y;
    size_t oS  = oYV + SZ_YV;

    bf16_t* Wb    = (bf16_t*)(ws + oWB);
    bf16_t* Wqkv  = Wb;
    bf16_t* Wproj = Wb + 27648;
    bf16_t* Wfc1  = Wb + 36864;
    bf16_t* Wfc2  = Wb + 73728;
    bf16_t* hp    = (bf16_t*)(ws + oHP);   // o_rows / h2
    bf16_t* Y     = (bf16_t*)(ws + oY);    // q,k; V goes straight to Yv
    bf16_t* Yv    = (bf16_t*)(ws + oYV);
    bf16_t* Pb    = (bf16_t*)(ws + oY);    // P aliases Y
    bf16_t* Sb    = (bf16_t*)(ws + oS);    // S bf16
    float*  x2    = (float*)(ws + oS);     // x2 aliases S
    float*  outp  = (float*)d_out;

    dim3 blk(256);

    // 1. weights -> bf16
    conv_w<<<dim3(432), blk, 0, stream>>>(qkv_w, proj_w, fc1_w, fc2_w, Wb);
    // 2. QKV gemm with FUSED LN1+permute -> Y (q,k) + Yv (V transposed)
    qkv_fused<<<dim3(432), blk, 0, stream>>>(x, Wqkv, Y, qkv_b, Yv, ln1_g, ln1_b);
    // 3. S = Q@K^T -> bf16  (8-phase 256^2, 81 blocks x 3 heads)
    gemm_bt8<1><<<dim3(81, 1, 3), dim3(512), 0, stream>>>(Y, Y + 3 * YSTR, Sb,
                                                          1536, YSTR, YSTR, SSTR, SCALE_Q);
    // 4. softmax (wave/row, vectorized) -> P
    softmax_k<<<dim3(576, 1, 3), blk, 0, stream>>>(Sb, Pb, SSTR, SSTR);
    // 5. O = P@V^T -> o_rows in hp  (8-phase 256^2, 54 blocks x 3 heads)
    gemm_bt8<2><<<dim3(54, 1, 3), dim3(512), 0, stream>>>(Pb, Yv, hp,
                                                          2304, SSTR, YSTR, 0, 0.f);
    // 6. proj + residual -> x2 (f32) + fused LN2 -> h2 (hp)
    gemm_ws<96, 96, 96, 5><<<dim3(432), blk, 0, stream>>>(hp, Wproj, x2, proj_b, x,
                                                          hp, ln2_g, ln2_b);
    // 7. fused MLP v3b (fc1+GELU+fc2+residual) -> out
    mlp_fused<<<dim3(864), blk, 0, stream>>>(hp, Wfc1, Wfc2, fc1_b, fc2_b, x2, outp);
}

// Round 11
// 334.631 us; speedup vs baseline: 1.0407x; 1.0407x over previous
//
#include <hip/hip_runtime.h>
#include <hip/hip_bf16.h>
#include <math.h>

typedef __bf16 bf16_t;
typedef __bf16 bf16x8 __attribute__((ext_vector_type(8)));
typedef __bf16 bf16x4 __attribute__((ext_vector_type(4)));
typedef float f32x4 __attribute__((ext_vector_type(4)));

#define AS1q __attribute__((address_space(1)))
#define AS3q __attribute__((address_space(3)))

__device__ __forceinline__ void gload_lds16(const bf16_t* g, bf16_t* l) {
    __builtin_amdgcn_global_load_lds((AS1q void*)g, (AS3q void*)l, 16, 0, 0);
}

// ------------------------------------------------------------------
// constants (B=1, H=W=T=48, C=96, nh=3, hd=32)
// ------------------------------------------------------------------
#define LROWS   110592
#define CDIM    96
#define NTOK    2304
#define FDIM    1536
#define YSTR    3538944ll     // 2304*1536
#define SSTR    5308416ll     // 2304*2304
#define SCALE_Q 0.1767766952966369f

// ------------------------------------------------------------------
// exact-erf GELU, branch-free (A&S 7.1.26, |erf err| <= 1.5e-7)
// ------------------------------------------------------------------
__device__ __forceinline__ float gelu_f(float v) {
    float xs = v * 0.70710678118654752f;
    float a  = fabsf(xs);
    float t  = __builtin_amdgcn_rcpf(fmaf(0.3275911f, a, 1.0f));
    float p  = t * fmaf(t, fmaf(t, fmaf(t, fmaf(t, 1.061405429f, -1.453152027f),
                                        1.421413741f), -0.284496736f), 0.254829592f);
    float e  = __expf(-a * a);
    float erfx = copysignf(fmaf(-p, e, 1.0f), xs);
    return 0.5f * v * (1.0f + erfx);
}

// ------------------------------------------------------------------
// weight fp32 -> bf16
// ------------------------------------------------------------------
__global__ __launch_bounds__(256)
void conv_w(const float* __restrict__ a, const float* __restrict__ b,
            const float* __restrict__ c, const float* __restrict__ d,
            bf16_t* __restrict__ out)
{
    int i = blockIdx.x * 256 + threadIdx.x;
    float v;
    if (i < 27648)       v = a[i];
    else if (i < 36864)  v = b[i - 27648];
    else if (i < 73728)  v = c[i - 36864];
    else                 v = d[i - 73728];
    out[i] = (bf16_t)v;
}

// ------------------------------------------------------------------
// row softmax over 2304, S bf16 -> P bf16.  One WAVE per row (no LDS).
// 16B/lane loads (bf16x8 x4 + bf16x4 tail) — G13 sweet spot.
// Coverage audited: t=0..3 -> elems (t*64+lane)*8..+7 = 0..2047;
// tail -> 2048 + lane*4..+3 = 2048..2303.  Row stride 4608B ≡ 0 mod
// 16 -> all bf16x8 loads 16B-aligned; tail 8B-aligned.  No LDS, no
// barriers -> no hang/fault path (R10 bench failure = infra flake).
// ------------------------------------------------------------------
__global__ __launch_bounds__(256)
void softmax_k(const bf16_t* __restrict__ S, bf16_t* __restrict__ P,
               long long sZ, long long pZ)
{
    int wv = threadIdx.x >> 6, lane = threadIdx.x & 63;
    int row = blockIdx.x * 4 + wv;
    const bf16_t* sr = S + (size_t)blockIdx.z * sZ + (size_t)row * NTOK;
    bf16_t* pr = P + (size_t)blockIdx.z * pZ + (size_t)row * NTOK;
    float v[36];
    float mx = -1e30f;
    #pragma unroll
    for (int t = 0; t < 4; t++) {
        bf16x8 c = *(const bf16x8*)(sr + (size_t)(t * 64 + lane) * 8);
        #pragma unroll
        for (int j = 0; j < 8; j++) { v[t*8+j] = (float)c[j]; mx = fmaxf(mx, v[t*8+j]); }
    }
    {
        bf16x4 c = *(const bf16x4*)(sr + 2048 + (size_t)lane * 4);
        #pragma unroll
        for (int j = 0; j < 4; j++) { v[32+j] = (float)c[j]; mx = fmaxf(mx, v[32+j]); }
    }
    #pragma unroll
    for (int off = 32; off > 0; off >>= 1) mx = fmaxf(mx, __shfl_xor(mx, off, 64));
    float sum = 0.f;
    #pragma unroll
    for (int j = 0; j < 36; j++) { v[j] = __expf(v[j] - mx); sum += v[j]; }
    #pragma unroll
    for (int off = 32; off > 0; off >>= 1) sum += __shfl_xor(sum, off, 64);
    float inv = 1.f / sum;
    #pragma unroll
    for (int t = 0; t < 4; t++) {
        bf16x8 o;
        #pragma unroll
        for (int j = 0; j < 8; j++) o[j] = (bf16_t)(v[t*8+j] * inv);
        *(bf16x8*)(pr + (size_t)(t * 64 + lane) * 8) = o;
    }
    {
        bf16x4 o;
        #pragma unroll
        for (int j = 0; j < 4; j++) o[j] = (bf16_t)(v[32+j] * inv);
        *(bf16x4*)(pr + 2048 + (size_t)lane * 4) = o;
    }
}

// ------------------------------------------------------------------
// bf16 MFMA GEMM (attention):  C[M,N] = A[M,K] @ W[N,K]^T
// BM=128, BK=64, 2x2 waves; XOR swizzle -> 0 conflicts; XCD swizzle.
// R5-proven: hoisted staging pointers (VALUBusy 34->17%, 58.8us,
// 832 TF).  PERMANENTLY PARKED: three deep-pipeline rewrites (R2
// 2-phase 97us, R4 coarse 256^2 81us, R9 fine 8-phase 78us) all lost
// to this 2-barrier + multi-block-TLP structure at this shape.
// EPI: 1=S bf16 (*scale)   2=PV scatter (o_rows)
// ------------------------------------------------------------------
template<int BN, int EPI, int NBY>
__global__ __launch_bounds__(256, 2)
void gemm_bt(const bf16_t* __restrict__ A, const bf16_t* __restrict__ W,
             void* __restrict__ out, int K,
             long long aZ, long long wZ, long long oZ, float scale)
{
    constexpr int BM = 128, BK = 64;
    constexpr int MI = 4;
    constexpr int NT = BN / 32;
    constexpr int NB = 18 * NBY;
    constexpr int CHK = (NB + 7) / 8;
    __shared__ bf16_t As[BM * BK];
    __shared__ bf16_t Bs[BN * BK];

    int id = blockIdx.x;
    int id2 = (id & 7) * CHK + (id >> 3);
    if (id2 >= NB) return;
    int p  = id2 / 108;
    int r_ = id2 - p * 108;
    int by = p * 6 + (r_ % 6);
    int bx = r_ / 6;

    const int tid = threadIdx.x;
    const int wave = tid >> 6, lane = tid & 63;
    const int quad = lane >> 4, l16 = lane & 15;
    const int wm = wave & 1, wn = wave >> 1;
    const int z = blockIdx.z;
    A += (size_t)z * aZ;
    W += (size_t)z * wZ;
    const int m0 = bx * BM, n0 = by * BN;

    f32x4 acc[MI][NT];
    #pragma unroll
    for (int i = 0; i < MI; i++)
        #pragma unroll
        for (int j = 0; j < NT; j++) { f32x4 zz = {0.f, 0.f, 0.f, 0.f}; acc[i][j] = zz; }

    const int srow = lane >> 3;
    const int scol = lane & 7;

    // hoisted per-thread staging pointers (loop-invariant except +k0)
    constexpr int NA = BM / 32;            // 4 A-chunks per wave
    constexpr int NBC = BN / 32;           // 4 B-chunks per wave (BN=128)
    const bf16_t* pa[NA]; bf16_t* la[NA];
    #pragma unroll
    for (int t = 0; t < NA; t++) {
        int it = t * 4 + wave;
        int r = it * 8 + srow;
        int cg = scol ^ (r & 7);
        pa[t] = A + (size_t)(m0 + r) * K + cg * 8;
        la[t] = &As[it * 512];
    }
    const bf16_t* pb[NBC]; bf16_t* lb[NBC];
    #pragma unroll
    for (int t = 0; t < NBC; t++) {
        int it = t * 4 + wave;
        int r = it * 8 + srow;
        int cg = scol ^ (r & 7);
        pb[t] = W + (size_t)(n0 + r) * K + cg * 8;
        lb[t] = &Bs[it * 512];
    }

    for (int k0 = 0; k0 < K; k0 += BK) {
        __syncthreads();
        #pragma unroll
        for (int t = 0; t < NA; t++)  gload_lds16(pa[t] + k0, la[t]);
        #pragma unroll
        for (int t = 0; t < NBC; t++) gload_lds16(pb[t] + k0, lb[t]);
        __syncthreads();

        bf16x8 af[MI][2], bfr[NT][2];
        #pragma unroll
        for (int i = 0; i < MI; i++) {
            int r = wm * 64 + i * 16 + l16;
            #pragma unroll
            for (int kk = 0; kk < 2; kk++)
                af[i][kk] = *(const bf16x8*)&As[r * 64 + (((kk * 4 + quad) ^ (r & 7)) << 3)];
        }
        #pragma unroll
        for (int j = 0; j < NT; j++) {
            int c = wn * (BN / 2) + j * 16 + l16;
            #pragma unroll
            for (int kk = 0; kk < 2; kk++)
                bfr[j][kk] = *(const bf16x8*)&Bs[c * 64 + (((kk * 4 + quad) ^ (c & 7)) << 3)];
        }
        #pragma unroll
        for (int kk = 0; kk < 2; kk++)
            #pragma unroll
            for (int i = 0; i < MI; i++)
                #pragma unroll
                for (int j = 0; j < NT; j++)
                    acc[i][j] = __builtin_amdgcn_mfma_f32_16x16x32_bf16(af[i][kk], bfr[j][kk], acc[i][j], 0, 0, 0);
    }

    #pragma unroll
    for (int i = 0; i < MI; i++)
        #pragma unroll
        for (int j = 0; j < NT; j++)
            #pragma unroll
            for (int ri = 0; ri < 4; ri++) {
                int r = m0 + wm * 64 + i * 16 + quad * 4 + ri;
                int c = n0 + wn * (BN / 2) + j * 16 + l16;
                float v = acc[i][j][ri];
                if constexpr (EPI == 1) {
                    bf16_t* op = (bf16_t*)out + (size_t)z * oZ;
                    op[(size_t)r * NTOK + c] = (bf16_t)(v * scale);
                } else {
                    int b = r / 48, rr = r - b * 48;
                    ((bf16_t*)out)[((size_t)(b * NTOK + rr * 48 + z * 16)) * CDIM + c] = (bf16_t)v;
                }
            }
}

// ------------------------------------------------------------------
// QKV GEMM with FUSED LN1 + axial permute (R8-proven, -22us):
// C[M,288] = LN1(x)[M,96] @ Wqkv^T, A-rows computed inline.
// ------------------------------------------------------------------
__global__ __launch_bounds__(256, 2)
void qkv_fused(const float* __restrict__ X, const bf16_t* __restrict__ Wg,
               bf16_t* __restrict__ out, const float* __restrict__ bias,
               bf16_t* __restrict__ outv,
               const float* __restrict__ g1, const float* __restrict__ b1)
{
    constexpr int N = 288, K = 96;
    constexpr int KP = K + 8;
    constexpr int NT = N / 16;
    constexpr int KI = K / 32;     // 3
    __shared__ __attribute__((aligned(16))) bf16_t Ws[N * KP];

    const int tid = threadIdx.x;
    const int wave = tid >> 6, lane = tid & 63;
    const int quad = lane >> 4, l16 = lane & 15;
    const int m0 = blockIdx.x * 256;

    constexpr int CH = N * K / 8;
    for (int c = tid; c < CH; c += 256) {
        int row = c / (K / 8), kc = c - row * (K / 8);
        bf16x8 w = *(const bf16x8*)(Wg + row * K + kc * 8);
        *(bf16x8*)(Ws + row * KP + kc * 8) = w;
    }
    __syncthreads();

    const int t = m0 / NTOK;
    const int nb = m0 - t * NTOK;

    // per-lane gamma/beta for cols quad*8 + kk*32 + (0..7)
    f32x4 gv[KI][2], bv[KI][2];
    #pragma unroll
    for (int kk = 0; kk < KI; kk++) {
        const float* gp = g1 + quad * 8 + kk * 32;
        const float* bp = b1 + quad * 8 + kk * 32;
        gv[kk][0] = *(const f32x4*)gp;     gv[kk][1] = *(const f32x4*)(gp + 4);
        bv[kk][0] = *(const f32x4*)bp;     bv[kk][1] = *(const f32x4*)(bp + 4);
    }

    // A fragments with inline LN (row l = (nb+wave*64+l16+i*16)*48 + t)
    bf16x8 af[4][KI];
    #pragma unroll
    for (int i = 0; i < 4; i++) {
        size_t l = (size_t)(nb + wave * 64 + l16 + i * 16) * 48 + t;
        const float* xr = X + l * 96 + quad * 8;
        f32x4 xv[KI][2];
        float s1 = 0.f, s2 = 0.f;
        #pragma unroll
        for (int kk = 0; kk < KI; kk++) {
            xv[kk][0] = *(const f32x4*)(xr + kk * 32);
            xv[kk][1] = *(const f32x4*)(xr + kk * 32 + 4);
            #pragma unroll
            for (int h = 0; h < 2; h++)
                #pragma unroll
                for (int j = 0; j < 4; j++) {
                    float v = xv[kk][h][j];
                    s1 += v; s2 += v * v;
                }
        }
        // cross-quad reduce (lanes l16, +16, +32, +48 share the row)
        s1 += __shfl_xor(s1, 16, 64);  s1 += __shfl_xor(s1, 32, 64);
        s2 += __shfl_xor(s2, 16, 64);  s2 += __shfl_xor(s2, 32, 64);
        float mean = s1 * (1.f / 96.f);
        float var  = s2 * (1.f / 96.f) - mean * mean;
        float rstd = rsqrtf(var + 1e-5f);
        #pragma unroll
        for (int kk = 0; kk < KI; kk++)
            #pragma unroll
            for (int h = 0; h < 2; h++)
                #pragma unroll
                for (int j = 0; j < 4; j++)
                    af[i][kk][h * 4 + j] =
                        (bf16_t)((xv[kk][h][j] - mean) * rstd * gv[kk][h][j] + bv[kk][h][j]);
    }

    #pragma unroll 2
    for (int nt = 0; nt < NT; nt++) {
        bf16x8 bfr[KI];
        #pragma unroll
        for (int kk = 0; kk < KI; kk++)
            bfr[kk] = *(const bf16x8*)(Ws + (nt * 16 + l16) * KP + kk * 32 + quad * 8);
        f32x4 a4[4];
        #pragma unroll
        for (int i = 0; i < 4; i++) { f32x4 zz = {0.f, 0.f, 0.f, 0.f}; a4[i] = zz; }
        #pragma unroll
        for (int kk = 0; kk < KI; kk++)
            #pragma unroll
            for (int i = 0; i < 4; i++)
                a4[i] = __builtin_amdgcn_mfma_f32_16x16x32_bf16(af[i][kk], bfr[kk], a4[i], 0, 0, 0);

        int c = nt * 16 + l16;
        int jj = t * 288 + c;
        int g = jj / FDIM, mm = jj - g * FDIM;
        float bvv = bias[c];
        if (g < 6) {
            bf16_t* yp = out + (size_t)g * YSTR + mm;
            #pragma unroll
            for (int i = 0; i < 4; i++)
                #pragma unroll
                for (int ri = 0; ri < 4; ri++) {
                    int n = nb + wave * 64 + i * 16 + quad * 4 + ri;
                    yp[(size_t)n * FDIM] = (bf16_t)(a4[i][ri] + bvv);
                }
        } else {
            bf16_t* vp = outv + (size_t)(g - 6) * YSTR + (size_t)mm * NTOK;
            #pragma unroll
            for (int i = 0; i < 4; i++) {
                int n0q = nb + wave * 64 + i * 16 + quad * 4;
                bf16x4 o;
                #pragma unroll
                for (int ri = 0; ri < 4; ri++) o[ri] = (bf16_t)(a4[i][ri] + bvv);
                *(bf16x4*)(vp + n0q) = o;
            }
        }
    }
}

// ------------------------------------------------------------------
// Weight-resident GEMM (proj path):  C[M,N] = A[M,K] @ W[N,K]^T.
// EPI 5: proj+bias+residual -> out f32 AND fused LayerNorm -> out2 bf16
// ------------------------------------------------------------------
template<int N, int K, int KC, int EPI>
__global__ __launch_bounds__(256, 2)
void gemm_ws(const bf16_t* __restrict__ A, const bf16_t* __restrict__ Wg,
             void* __restrict__ out, const float* __restrict__ bias,
             const float* __restrict__ resid,
             bf16_t* __restrict__ out2, const float* __restrict__ g2,
             const float* __restrict__ b2)
{
    constexpr int KP = K + 8;
    constexpr int NT = N / 16;
    constexpr int KI = KC / 32;
    __shared__ __attribute__((aligned(16))) bf16_t Ws[N * KP];

    const int tid = threadIdx.x;
    const int wave = tid >> 6, lane = tid & 63;
    const int quad = lane >> 4, l16 = lane & 15;
    const int m0 = blockIdx.x * 256;

    constexpr int CH = N * K / 8;
    for (int c = tid; c < CH; c += 256) {
        int row = c / (K / 8), kc = c - row * (K / 8);
        bf16x8 w = *(const bf16x8*)(Wg + row * K + kc * 8);
        *(bf16x8*)(Ws + row * KP + kc * 8) = w;
    }
    __syncthreads();

    const bf16_t* Ar = A + (size_t)(m0 + wave * 64 + l16) * K + quad * 8;

    f32x4 acc[4][NT];
    #pragma unroll
    for (int i = 0; i < 4; i++)
        #pragma unroll
        for (int j = 0; j < NT; j++) { f32x4 zz = {0.f, 0.f, 0.f, 0.f}; acc[i][j] = zz; }
    for (int kc0 = 0; kc0 < K; kc0 += KC) {
        bf16x8 af[4][KI];
        #pragma unroll
        for (int i = 0; i < 4; i++)
            #pragma unroll
            for (int kk = 0; kk < KI; kk++)
                af[i][kk] = *(const bf16x8*)(Ar + (size_t)i * 16 * K + kc0 + kk * 32);
        #pragma unroll
        for (int nt = 0; nt < NT; nt++) {
            #pragma unroll
            for (int kk = 0; kk < KI; kk++) {
                bf16x8 b = *(const bf16x8*)(Ws + (nt * 16 + l16) * KP + kc0 + kk * 32 + quad * 8);
                #pragma unroll
                for (int i = 0; i < 4; i++)
                    acc[i][nt] = __builtin_amdgcn_mfma_f32_16x16x32_bf16(af[i][kk], b, acc[i][nt], 0, 0, 0);
            }
        }
    }
    if constexpr (EPI == 5) {
        float bv[NT], gv[NT], bb[NT];
        #pragma unroll
        for (int nt = 0; nt < NT; nt++) {
            int c = nt * 16 + l16;
            bv[nt] = bias[c]; gv[nt] = g2[c]; bb[nt] = b2[c];
        }
        #pragma unroll
        for (int i = 0; i < 4; i++)
            #pragma unroll
            for (int ri = 0; ri < 4; ri++) {
                int r = m0 + wave * 64 + i * 16 + quad * 4 + ri;
                float u[NT];
                float s = 0.f;
                #pragma unroll
                for (int nt = 0; nt < NT; nt++) {
                    int c = nt * 16 + l16;
                    u[nt] = acc[i][nt][ri] + bv[nt] + resid[(size_t)r * N + c];
                    ((float*)out)[(size_t)r * N + c] = u[nt];
                    s += u[nt];
                }
                #pragma unroll
                for (int off = 8; off > 0; off >>= 1) s += __shfl_xor(s, off, 64);
                float mean = s * (1.f / 96.f);
                float vs = 0.f;
                #pragma unroll
                for (int nt = 0; nt < NT; nt++) {
                    float dd = u[nt] - mean;
                    u[nt] = dd;
                    vs += dd * dd;
                }
                #pragma unroll
                for (int off = 8; off > 0; off >>= 1) vs += __shfl_xor(vs, off, 64);
                float rstd = rsqrtf(vs * (1.f / 96.f) + 1e-5f);
                #pragma unroll
                for (int nt = 0; nt < NT; nt++) {
                    int c = nt * 16 + l16;
                    out2[(size_t)r * N + c] = (bf16_t)(u[nt] * rstd * gv[nt] + bb[nt]);
                }
            }
    }
}

// ------------------------------------------------------------------
// Fused MLP v3b: out = x2 + fc2(gelu(fc1(h2)+b1))+b2  (t1 never in HBM)
// BM=128, 4 waves x 32 rows, one barrier/chunk (Tb wave-private),
// 4 blocks/CU, A&S erf GELU, conflict-free Tb stride 44 (R7).
// ------------------------------------------------------------------
__global__ __launch_bounds__(256, 4)
void mlp_fused(const bf16_t* __restrict__ A, const bf16_t* __restrict__ W1g,
               const bf16_t* __restrict__ W2g, const float* __restrict__ b1,
               const float* __restrict__ b2, const float* __restrict__ resid,
               float* __restrict__ out)
{
    constexpr int KP1 = 104;   // 96+8: B-frag rows stride 52 dwords (uniform spread)
    constexpr int TBS = 44;    // Tb row stride: 22 dw -> conflict-free
    __shared__ __attribute__((aligned(16))) bf16_t W1c[2][32 * KP1]; // 2x6656 B
    __shared__ __attribute__((aligned(16))) bf16_t W2c[2][96 * 40];  // 2x7680 B
    __shared__ __attribute__((aligned(16))) bf16_t Tb[128 * TBS];    // 11264 B

    const int tid = threadIdx.x;
    const int wave = tid >> 6, lane = tid & 63;
    const int quad = lane >> 4, l16 = lane & 15;
    const int m0 = blockIdx.x * 128;

    // A rows resident (full K=96): wave handles 32 rows (2 m-tiles)
    const bf16_t* Ar = A + (size_t)(m0 + wave * 32 + l16) * 96 + quad * 8;
    bf16x8 af[2][3];
    #pragma unroll
    for (int i = 0; i < 2; i++)
        #pragma unroll
        for (int kk = 0; kk < 3; kk++)
            af[i][kk] = *(const bf16x8*)(Ar + (size_t)i * 16 * 96 + kk * 32);

    // prefetch chunk 0 of W1 (32x96) and W2 (96 x cols 0..32) to regs
    bf16x4 w1n[3], w2n[3];
    #pragma unroll
    for (int q = 0; q < 3; q++) {
        int e = q * 256 + tid;
        w1n[q] = *(const bf16x4*)(W1g + e * 4);                       // rows 0..32 contiguous
        int row = e >> 3, sub = e & 7;
        w2n[q] = *(const bf16x4*)(W2g + row * 384 + sub * 4);
    }
    #pragma unroll
    for (int q = 0; q < 3; q++) {
        int e = q * 256 + tid;
        int r1 = e / 24, s1 = e - r1 * 24;
        *(bf16x4*)(&W1c[0][r1 * KP1 + s1 * 4]) = w1n[q];
        int row = e >> 3, sub = e & 7;
        *(bf16x4*)(&W2c[0][row * 40 + sub * 4]) = w2n[q];
    }
    __syncthreads();

    f32x4 acc2[2][6];
    #pragma unroll
    for (int i = 0; i < 2; i++)
        #pragma unroll
        for (int j = 0; j < 6; j++) { f32x4 zz = {0.f, 0.f, 0.f, 0.f}; acc2[i][j] = zz; }

    for (int c = 0; c < 12; c++) {
        const int pb = c & 1;
        // prefetch chunk c+1 to regs (vmcnt hidden by fc1 MFMAs + GELU)
        if (c < 11) {
            #pragma unroll
            for (int q = 0; q < 3; q++) {
                int e = q * 256 + tid;
                w1n[q] = *(const bf16x4*)(W1g + (c + 1) * 3072 + e * 4);
                int row = e >> 3, sub = e & 7;
                w2n[q] = *(const bf16x4*)(W2g + row * 384 + (c + 1) * 32 + sub * 4);
            }
        }
        // fc1 chunk: cols c*32..+32  (12 MFMA/wave), reads W1c[pb]
        f32x4 a1[2][2];
        #pragma unroll
        for (int i = 0; i < 2; i++)
            #pragma unroll
            for (int s = 0; s < 2; s++) { f32x4 zz = {0.f, 0.f, 0.f, 0.f}; a1[i][s] = zz; }
        #pragma unroll
        for (int s = 0; s < 2; s++) {
            int n = s * 16 + l16;
            #pragma unroll
            for (int kk = 0; kk < 3; kk++) {
                bf16x8 b = *(const bf16x8*)(&W1c[pb][n * KP1 + kk * 32 + quad * 8]);
                #pragma unroll
                for (int i = 0; i < 2; i++)
                    a1[i][s] = __builtin_amdgcn_mfma_f32_16x16x32_bf16(af[i][kk], b, a1[i][s], 0, 0, 0);
            }
        }
        // GELU -> Tb (wave-private rows; no barrier needed before fc2)
        #pragma unroll
        for (int s = 0; s < 2; s++) {
            int n = c * 32 + s * 16 + l16;
            float bv = b1[n];
            #pragma unroll
            for (int i = 0; i < 2; i++)
                #pragma unroll
                for (int ri = 0; ri < 4; ri++) {
                    float u = gelu_f(a1[i][s][ri] + bv);
                    Tb[(wave * 32 + i * 16 + quad * 4 + ri) * TBS + s * 16 + l16] = (bf16_t)u;
                }
        }
        // stage chunk c+1 into buffer pb^1 (its last readers finished
        // before barrier c-1 -> safe with the single end-of-chunk barrier)
        if (c < 11) {
            #pragma unroll
            for (int q = 0; q < 3; q++) {
                int e = q * 256 + tid;
                int r1 = e / 24, s1 = e - r1 * 24;
                *(bf16x4*)(&W1c[pb ^ 1][r1 * KP1 + s1 * 4]) = w1n[q];
                int row = e >> 3, sub = e & 7;
                *(bf16x4*)(&W2c[pb ^ 1][row * 40 + sub * 4]) = w2n[q];
            }
        }
        // fc2 partial (K=32): 12 MFMA/wave, reads own Tb rows + W2c[pb]
        bf16x8 a2[2];
        #pragma unroll
        for (int i = 0; i < 2; i++) {
            const bf16_t* tp = Tb + (wave * 32 + i * 16 + l16) * TBS + quad * 8;
            bf16x4 lo = *(const bf16x4*)tp;
            bf16x4 hi = *(const bf16x4*)(tp + 4);
            #pragma unroll
            for (int j = 0; j < 4; j++) { a2[i][j] = lo[j]; a2[i][j + 4] = hi[j]; }
        }
        #pragma unroll
        for (int nt = 0; nt < 6; nt++) {
            bf16x8 b = *(const bf16x8*)(&W2c[pb][(nt * 16 + l16) * 40 + quad * 8]);
            #pragma unroll
            for (int i = 0; i < 2; i++)
                acc2[i][nt] = __builtin_amdgcn_mfma_f32_16x16x32_bf16(a2[i], b, acc2[i][nt], 0, 0, 0);
        }
        __syncthreads();   // one barrier per chunk
    }

    // epilogue: + b2 + resid -> f32 out
    #pragma unroll
    for (int i = 0; i < 2; i++)
        #pragma unroll
        for (int nt = 0; nt < 6; nt++)
            #pragma unroll
            for (int ri = 0; ri < 4; ri++) {
                int r = m0 + wave * 32 + i * 16 + quad * 4 + ri;
                int cc = nt * 16 + l16;
                out[(size_t)r * 96 + cc] = acc2[i][nt][ri] + b2[cc] + resid[(size_t)r * 96 + cc];
            }
}

// ------------------------------------------------------------------
extern "C" void kernel_launch(void* const* d_in, const int* in_sizes, int n_in,
                              void* d_out, int out_size, void* d_ws, size_t ws_size,
                              hipStream_t stream)
{
    const float* x      = (const float*)d_in[0];
    const float* ln1_g  = (const float*)d_in[2];
    const float* ln1_b  = (const float*)d_in[3];
    const float* qkv_w  = (const float*)d_in[4];
    const float* qkv_b  = (const float*)d_in[5];
    const float* proj_w = (const float*)d_in[6];
    const float* proj_b = (const float*)d_in[7];
    const float* ln2_g  = (const float*)d_in[8];
    const float* ln2_b  = (const float*)d_in[9];
    const float* fc1_w  = (const float*)d_in[10];
    const float* fc1_b  = (const float*)d_in[11];
    const float* fc2_w  = (const float*)d_in[12];
    const float* fc2_b  = (const float*)d_in[13];

    // ---- workspace 170.1 MB (aliased by liveness) ----
    const size_t SZ_WB = 110592ull * 2;
    const size_t SZ_HP = 10616832ull * 2;
    const size_t SZ_Y  = 31850496ull * 2;
    const size_t SZ_YV = 10616832ull * 2;

    char* ws = (char*)d_ws;
    size_t oWB = 0;
    size_t oHP = oWB + SZ_WB;
    size_t oY  = oHP + SZ_HP;
    size_t oYV = oY + SZ_Y;
    size_t oS  = oYV + SZ_YV;

    bf16_t* Wb    = (bf16_t*)(ws + oWB);
    bf16_t* Wqkv  = Wb;
    bf16_t* Wproj = Wb + 27648;
    bf16_t* Wfc1  = Wb + 36864;
    bf16_t* Wfc2  = Wb + 73728;
    bf16_t* hp    = (bf16_t*)(ws + oHP);   // o_rows / h2
    bf16_t* Y     = (bf16_t*)(ws + oY);    // q,k; V goes straight to Yv
    bf16_t* Yv    = (bf16_t*)(ws + oYV);
    bf16_t* Pb    = (bf16_t*)(ws + oY);    // P aliases Y
    bf16_t* Sb    = (bf16_t*)(ws + oS);    // S bf16
    float*  x2    = (float*)(ws + oS);     // x2 aliases S
    float*  outp  = (float*)d_out;

    dim3 blk(256);

    // 1. weights -> bf16
    conv_w<<<dim3(432), blk, 0, stream>>>(qkv_w, proj_w, fc1_w, fc2_w, Wb);
    // 2. QKV gemm with FUSED LN1+permute -> Y (q,k) + Yv (V transposed)
    qkv_fused<<<dim3(432), blk, 0, stream>>>(x, Wqkv, Y, qkv_b, Yv, ln1_g, ln1_b);
    // 3. S = Q@K^T -> bf16
    gemm_bt<128, 1, 18><<<dim3(328, 1, 3), blk, 0, stream>>>(Y, Y + 3 * YSTR, Sb,
                                                             1536, YSTR, YSTR, SSTR, SCALE_Q);
    // 4. softmax (wave/row, 16B/lane vectorized) -> P
    softmax_k<<<dim3(576, 1, 3), blk, 0, stream>>>(Sb, Pb, SSTR, SSTR);
    // 5. O = P@V^T -> o_rows in hp
    gemm_bt<128, 2, 12><<<dim3(216, 1, 3), blk, 0, stream>>>(Pb, Yv, hp,
                                                             2304, SSTR, YSTR, 0, 0.f);
    // 6. proj + residual -> x2 (f32) + fused LN2 -> h2 (hp)
    gemm_ws<96, 96, 96, 5><<<dim3(432), blk, 0, stream>>>(hp, Wproj, x2, proj_b, x,
                                                          hp, ln2_g, ln2_b);
    // 7. fused MLP v3b (fc1+GELU+fc2+residual) -> out
    mlp_fused<<<dim3(864), blk, 0, stream>>>(hp, Wfc1, Wfc2, fc1_b, fc2_b, x2, outp);
}

// Round 12
// 321.290 us; speedup vs baseline: 1.0839x; 1.0415x over previous
//
#include <hip/hip_runtime.h>
#include <hip/hip_bf16.h>
#include <math.h>

typedef __bf16 bf16_t;
typedef __bf16 bf16x8 __attribute__((ext_vector_type(8)));
typedef __bf16 bf16x4 __attribute__((ext_vector_type(4)));
typedef float f32x4 __attribute__((ext_vector_type(4)));

#define AS1q __attribute__((address_space(1)))
#define AS3q __attribute__((address_space(3)))

__device__ __forceinline__ void gload_lds16(const bf16_t* g, bf16_t* l) {
    __builtin_amdgcn_global_load_lds((AS1q void*)g, (AS3q void*)l, 16, 0, 0);
}

// ------------------------------------------------------------------
// constants (B=1, H=W=T=48, C=96, nh=3, hd=32)
// ------------------------------------------------------------------
#define LROWS   110592
#define CDIM    96
#define NTOK    2304
#define FDIM    1536
#define YSTR    3538944ll     // 2304*1536
#define SSTR    5308416ll     // 2304*2304
#define SCALE_Q 0.1767766952966369f

// ------------------------------------------------------------------
// exact-erf GELU, branch-free.  R12: A&S 7.1.25 3-term rational
// (|erf err| <= 2.5e-5; through fc2 ~2e-5 — 3 orders below bf16
// rounding).  Saves 2 FMA/eval vs 7.1.26 on the mlp's dominant
// VALU phase (R11 PMC: VALUBusy 41.5%, ~24us of GELU issue).
// ------------------------------------------------------------------
__device__ __forceinline__ float gelu_f(float v) {
    float xs = v * 0.70710678118654752f;
    float a  = fabsf(xs);
    float t  = __builtin_amdgcn_rcpf(fmaf(0.47047f, a, 1.0f));
    float p  = t * fmaf(t, fmaf(t, 0.7478556f, -0.0958798f), 0.3480242f);
    float e  = __expf(-a * a);
    float erfx = copysignf(fmaf(-p, e, 1.0f), xs);
    return 0.5f * v * (1.0f + erfx);
}

// ------------------------------------------------------------------
// weight fp32 -> bf16
// ------------------------------------------------------------------
__global__ __launch_bounds__(256)
void conv_w(const float* __restrict__ a, const float* __restrict__ b,
            const float* __restrict__ c, const float* __restrict__ d,
            bf16_t* __restrict__ out)
{
    int i = blockIdx.x * 256 + threadIdx.x;
    float v;
    if (i < 27648)       v = a[i];
    else if (i < 36864)  v = b[i - 27648];
    else if (i < 73728)  v = c[i - 36864];
    else                 v = d[i - 73728];
    out[i] = (bf16_t)v;
}

// ------------------------------------------------------------------
// row softmax over 2304, S bf16 -> P bf16.  One WAVE per row (no LDS).
// R8-proven version (323.9us total) — R11's 16B variant reverted
// (confounded +11us run; discipline: bank the measured best).
// ------------------------------------------------------------------
__global__ __launch_bounds__(256)
void softmax_k(const bf16_t* __restrict__ S, bf16_t* __restrict__ P,
               long long sZ, long long pZ)
{
    int wv = threadIdx.x >> 6, lane = threadIdx.x & 63;
    int row = blockIdx.x * 4 + wv;
    const bf16_t* sr = S + (size_t)blockIdx.z * sZ + (size_t)row * NTOK;
    bf16_t* pr = P + (size_t)blockIdx.z * pZ + (size_t)row * NTOK;
    float v[36];
    float mx = -1e30f;
    #pragma unroll
    for (int t = 0; t < 9; t++) {
        bf16x4 c = *(const bf16x4*)(sr + (size_t)(t * 64 + lane) * 4);
        #pragma unroll
        for (int j = 0; j < 4; j++) { v[t*4+j] = (float)c[j]; mx = fmaxf(mx, v[t*4+j]); }
    }
    #pragma unroll
    for (int off = 32; off > 0; off >>= 1) mx = fmaxf(mx, __shfl_xor(mx, off, 64));
    float sum = 0.f;
    #pragma unroll
    for (int j = 0; j < 36; j++) { v[j] = __expf(v[j] - mx); sum += v[j]; }
    #pragma unroll
    for (int off = 32; off > 0; off >>= 1) sum += __shfl_xor(sum, off, 64);
    float inv = 1.f / sum;
    #pragma unroll
    for (int t = 0; t < 9; t++) {
        bf16x4 o;
        #pragma unroll
        for (int j = 0; j < 4; j++) o[j] = (bf16_t)(v[t*4+j] * inv);
        *(bf16x4*)(pr + (size_t)(t * 64 + lane) * 4) = o;
    }
}

// ------------------------------------------------------------------
// bf16 MFMA GEMM (attention):  C[M,N] = A[M,K] @ W[N,K]^T
// BM=128, BK=64, 2x2 waves; XOR swizzle -> 0 conflicts; XCD swizzle.
// R5-proven: hoisted staging pointers (VALUBusy 34->17%, ~58us,
// 832 TF).  PERMANENTLY PARKED: three deep-pipeline rewrites (R2
// 2-phase 97us, R4 coarse 256^2 81us, R9 fine 8-phase 78us) all lost
// to this 2-barrier + multi-block-TLP structure at this shape.
// EPI: 1=S bf16 (*scale)   2=PV scatter (o_rows)
// ------------------------------------------------------------------
template<int BN, int EPI, int NBY>
__global__ __launch_bounds__(256, 2)
void gemm_bt(const bf16_t* __restrict__ A, const bf16_t* __restrict__ W,
             void* __restrict__ out, int K,
             long long aZ, long long wZ, long long oZ, float scale)
{
    constexpr int BM = 128, BK = 64;
    constexpr int MI = 4;
    constexpr int NT = BN / 32;
    constexpr int NB = 18 * NBY;
    constexpr int CHK = (NB + 7) / 8;
    __shared__ bf16_t As[BM * BK];
    __shared__ bf16_t Bs[BN * BK];

    int id = blockIdx.x;
    int id2 = (id & 7) * CHK + (id >> 3);
    if (id2 >= NB) return;
    int p  = id2 / 108;
    int r_ = id2 - p * 108;
    int by = p * 6 + (r_ % 6);
    int bx = r_ / 6;

    const int tid = threadIdx.x;
    const int wave = tid >> 6, lane = tid & 63;
    const int quad = lane >> 4, l16 = lane & 15;
    const int wm = wave & 1, wn = wave >> 1;
    const int z = blockIdx.z;
    A += (size_t)z * aZ;
    W += (size_t)z * wZ;
    const int m0 = bx * BM, n0 = by * BN;

    f32x4 acc[MI][NT];
    #pragma unroll
    for (int i = 0; i < MI; i++)
        #pragma unroll
        for (int j = 0; j < NT; j++) { f32x4 zz = {0.f, 0.f, 0.f, 0.f}; acc[i][j] = zz; }

    const int srow = lane >> 3;
    const int scol = lane & 7;

    // hoisted per-thread staging pointers (loop-invariant except +k0)
    constexpr int NA = BM / 32;            // 4 A-chunks per wave
    constexpr int NBC = BN / 32;           // 4 B-chunks per wave (BN=128)
    const bf16_t* pa[NA]; bf16_t* la[NA];
    #pragma unroll
    for (int t = 0; t < NA; t++) {
        int it = t * 4 + wave;
        int r = it * 8 + srow;
        int cg = scol ^ (r & 7);
        pa[t] = A + (size_t)(m0 + r) * K + cg * 8;
        la[t] = &As[it * 512];
    }
    const bf16_t* pb[NBC]; bf16_t* lb[NBC];
    #pragma unroll
    for (int t = 0; t < NBC; t++) {
        int it = t * 4 + wave;
        int r = it * 8 + srow;
        int cg = scol ^ (r & 7);
        pb[t] = W + (size_t)(n0 + r) * K + cg * 8;
        lb[t] = &Bs[it * 512];
    }

    for (int k0 = 0; k0 < K; k0 += BK) {
        __syncthreads();
        #pragma unroll
        for (int t = 0; t < NA; t++)  gload_lds16(pa[t] + k0, la[t]);
        #pragma unroll
        for (int t = 0; t < NBC; t++) gload_lds16(pb[t] + k0, lb[t]);
        __syncthreads();

        bf16x8 af[MI][2], bfr[NT][2];
        #pragma unroll
        for (int i = 0; i < MI; i++) {
            int r = wm * 64 + i * 16 + l16;
            #pragma unroll
            for (int kk = 0; kk < 2; kk++)
                af[i][kk] = *(const bf16x8*)&As[r * 64 + (((kk * 4 + quad) ^ (r & 7)) << 3)];
        }
        #pragma unroll
        for (int j = 0; j < NT; j++) {
            int c = wn * (BN / 2) + j * 16 + l16;
            #pragma unroll
            for (int kk = 0; kk < 2; kk++)
                bfr[j][kk] = *(const bf16x8*)&Bs[c * 64 + (((kk * 4 + quad) ^ (c & 7)) << 3)];
        }
        #pragma unroll
        for (int kk = 0; kk < 2; kk++)
            #pragma unroll
            for (int i = 0; i < MI; i++)
                #pragma unroll
                for (int j = 0; j < NT; j++)
                    acc[i][j] = __builtin_amdgcn_mfma_f32_16x16x32_bf16(af[i][kk], bfr[j][kk], acc[i][j], 0, 0, 0);
    }

    #pragma unroll
    for (int i = 0; i < MI; i++)
        #pragma unroll
        for (int j = 0; j < NT; j++)
            #pragma unroll
            for (int ri = 0; ri < 4; ri++) {
                int r = m0 + wm * 64 + i * 16 + quad * 4 + ri;
                int c = n0 + wn * (BN / 2) + j * 16 + l16;
                float v = acc[i][j][ri];
                if constexpr (EPI == 1) {
                    bf16_t* op = (bf16_t*)out + (size_t)z * oZ;
                    op[(size_t)r * NTOK + c] = (bf16_t)(v * scale);
                } else {
                    int b = r / 48, rr = r - b * 48;
                    ((bf16_t*)out)[((size_t)(b * NTOK + rr * 48 + z * 16)) * CDIM + c] = (bf16_t)v;
                }
            }
}

// ------------------------------------------------------------------
// QKV GEMM with FUSED LN1 + axial permute (R8-proven, -22us):
// C[M,288] = LN1(x)[M,96] @ Wqkv^T, A-rows computed inline.
// ------------------------------------------------------------------
__global__ __launch_bounds__(256, 2)
void qkv_fused(const float* __restrict__ X, const bf16_t* __restrict__ Wg,
               bf16_t* __restrict__ out, const float* __restrict__ bias,
               bf16_t* __restrict__ outv,
               const float* __restrict__ g1, const float* __restrict__ b1)
{
    constexpr int N = 288, K = 96;
    constexpr int KP = K + 8;
    constexpr int NT = N / 16;
    constexpr int KI = K / 32;     // 3
    __shared__ __attribute__((aligned(16))) bf16_t Ws[N * KP];

    const int tid = threadIdx.x;
    const int wave = tid >> 6, lane = tid & 63;
    const int quad = lane >> 4, l16 = lane & 15;
    const int m0 = blockIdx.x * 256;

    constexpr int CH = N * K / 8;
    for (int c = tid; c < CH; c += 256) {
        int row = c / (K / 8), kc = c - row * (K / 8);
        bf16x8 w = *(const bf16x8*)(Wg + row * K + kc * 8);
        *(bf16x8*)(Ws + row * KP + kc * 8) = w;
    }
    __syncthreads();

    const int t = m0 / NTOK;
    const int nb = m0 - t * NTOK;

    // per-lane gamma/beta for cols quad*8 + kk*32 + (0..7)
    f32x4 gv[KI][2], bv[KI][2];
    #pragma unroll
    for (int kk = 0; kk < KI; kk++) {
        const float* gp = g1 + quad * 8 + kk * 32;
        const float* bp = b1 + quad * 8 + kk * 32;
        gv[kk][0] = *(const f32x4*)gp;     gv[kk][1] = *(const f32x4*)(gp + 4);
        bv[kk][0] = *(const f32x4*)bp;     bv[kk][1] = *(const f32x4*)(bp + 4);
    }

    // A fragments with inline LN (row l = (nb+wave*64+l16+i*16)*48 + t)
    bf16x8 af[4][KI];
    #pragma unroll
    for (int i = 0; i < 4; i++) {
        size_t l = (size_t)(nb + wave * 64 + l16 + i * 16) * 48 + t;
        const float* xr = X + l * 96 + quad * 8;
        f32x4 xv[KI][2];
        float s1 = 0.f, s2 = 0.f;
        #pragma unroll
        for (int kk = 0; kk < KI; kk++) {
            xv[kk][0] = *(const f32x4*)(xr + kk * 32);
            xv[kk][1] = *(const f32x4*)(xr + kk * 32 + 4);
            #pragma unroll
            for (int h = 0; h < 2; h++)
                #pragma unroll
                for (int j = 0; j < 4; j++) {
                    float v = xv[kk][h][j];
                    s1 += v; s2 += v * v;
                }
        }
        // cross-quad reduce (lanes l16, +16, +32, +48 share the row)
        s1 += __shfl_xor(s1, 16, 64);  s1 += __shfl_xor(s1, 32, 64);
        s2 += __shfl_xor(s2, 16, 64);  s2 += __shfl_xor(s2, 32, 64);
        float mean = s1 * (1.f / 96.f);
        float var  = s2 * (1.f / 96.f) - mean * mean;
        float rstd = rsqrtf(var + 1e-5f);
        #pragma unroll
        for (int kk = 0; kk < KI; kk++)
            #pragma unroll
            for (int h = 0; h < 2; h++)
                #pragma unroll
                for (int j = 0; j < 4; j++)
                    af[i][kk][h * 4 + j] =
                        (bf16_t)((xv[kk][h][j] - mean) * rstd * gv[kk][h][j] + bv[kk][h][j]);
    }

    #pragma unroll 2
    for (int nt = 0; nt < NT; nt++) {
        bf16x8 bfr[KI];
        #pragma unroll
        for (int kk = 0; kk < KI; kk++)
            bfr[kk] = *(const bf16x8*)(Ws + (nt * 16 + l16) * KP + kk * 32 + quad * 8);
        f32x4 a4[4];
        #pragma unroll
        for (int i = 0; i < 4; i++) { f32x4 zz = {0.f, 0.f, 0.f, 0.f}; a4[i] = zz; }
        #pragma unroll
        for (int kk = 0; kk < KI; kk++)
            #pragma unroll
            for (int i = 0; i < 4; i++)
                a4[i] = __builtin_amdgcn_mfma_f32_16x16x32_bf16(af[i][kk], bfr[kk], a4[i], 0, 0, 0);

        int c = nt * 16 + l16;
        int jj = t * 288 + c;
        int g = jj / FDIM, mm = jj - g * FDIM;
        float bvv = bias[c];
        if (g < 6) {
            bf16_t* yp = out + (size_t)g * YSTR + mm;
            #pragma unroll
            for (int i = 0; i < 4; i++)
                #pragma unroll
                for (int ri = 0; ri < 4; ri++) {
                    int n = nb + wave * 64 + i * 16 + quad * 4 + ri;
                    yp[(size_t)n * FDIM] = (bf16_t)(a4[i][ri] + bvv);
                }
        } else {
            bf16_t* vp = outv + (size_t)(g - 6) * YSTR + (size_t)mm * NTOK;
            #pragma unroll
            for (int i = 0; i < 4; i++) {
                int n0q = nb + wave * 64 + i * 16 + quad * 4;
                bf16x4 o;
                #pragma unroll
                for (int ri = 0; ri < 4; ri++) o[ri] = (bf16_t)(a4[i][ri] + bvv);
                *(bf16x4*)(vp + n0q) = o;
            }
        }
    }
}

// ------------------------------------------------------------------
// Weight-resident GEMM (proj path):  C[M,N] = A[M,K] @ W[N,K]^T.
// EPI 5: proj+bias+residual -> out f32 AND fused LayerNorm -> out2 bf16
// ------------------------------------------------------------------
template<int N, int K, int KC, int EPI>
__global__ __launch_bounds__(256, 2)
void gemm_ws(const bf16_t* __restrict__ A, const bf16_t* __restrict__ Wg,
             void* __restrict__ out, const float* __restrict__ bias,
             const float* __restrict__ resid,
             bf16_t* __restrict__ out2, const float* __restrict__ g2,
             const float* __restrict__ b2)
{
    constexpr int KP = K + 8;
    constexpr int NT = N / 16;
    constexpr int KI = KC / 32;
    __shared__ __attribute__((aligned(16))) bf16_t Ws[N * KP];

    const int tid = threadIdx.x;
    const int wave = tid >> 6, lane = tid & 63;
    const int quad = lane >> 4, l16 = lane & 15;
    const int m0 = blockIdx.x * 256;

    constexpr int CH = N * K / 8;
    for (int c = tid; c < CH; c += 256) {
        int row = c / (K / 8), kc = c - row * (K / 8);
        bf16x8 w = *(const bf16x8*)(Wg + row * K + kc * 8);
        *(bf16x8*)(Ws + row * KP + kc * 8) = w;
    }
    __syncthreads();

    const bf16_t* Ar = A + (size_t)(m0 + wave * 64 + l16) * K + quad * 8;

    f32x4 acc[4][NT];
    #pragma unroll
    for (int i = 0; i < 4; i++)
        #pragma unroll
        for (int j = 0; j < NT; j++) { f32x4 zz = {0.f, 0.f, 0.f, 0.f}; acc[i][j] = zz; }
    for (int kc0 = 0; kc0 < K; kc0 += KC) {
        bf16x8 af[4][KI];
        #pragma unroll
        for (int i = 0; i < 4; i++)
            #pragma unroll
            for (int kk = 0; kk < KI; kk++)
                af[i][kk] = *(const bf16x8*)(Ar + (size_t)i * 16 * K + kc0 + kk * 32);
        #pragma unroll
        for (int nt = 0; nt < NT; nt++) {
            #pragma unroll
            for (int kk = 0; kk < KI; kk++) {
                bf16x8 b = *(const bf16x8*)(Ws + (nt * 16 + l16) * KP + kc0 + kk * 32 + quad * 8);
                #pragma unroll
                for (int i = 0; i < 4; i++)
                    acc[i][nt] = __builtin_amdgcn_mfma_f32_16x16x32_bf16(af[i][kk], b, acc[i][nt], 0, 0, 0);
            }
        }
    }
    if constexpr (EPI == 5) {
        float bv[NT], gv[NT], bb[NT];
        #pragma unroll
        for (int nt = 0; nt < NT; nt++) {
            int c = nt * 16 + l16;
            bv[nt] = bias[c]; gv[nt] = g2[c]; bb[nt] = b2[c];
        }
        #pragma unroll
        for (int i = 0; i < 4; i++)
            #pragma unroll
            for (int ri = 0; ri < 4; ri++) {
                int r = m0 + wave * 64 + i * 16 + quad * 4 + ri;
                float u[NT];
                float s = 0.f;
                #pragma unroll
                for (int nt = 0; nt < NT; nt++) {
                    int c = nt * 16 + l16;
                    u[nt] = acc[i][nt][ri] + bv[nt] + resid[(size_t)r * N + c];
                    ((float*)out)[(size_t)r * N + c] = u[nt];
                    s += u[nt];
                }
                #pragma unroll
                for (int off = 8; off > 0; off >>= 1) s += __shfl_xor(s, off, 64);
                float mean = s * (1.f / 96.f);
                float vs = 0.f;
                #pragma unroll
                for (int nt = 0; nt < NT; nt++) {
                    float dd = u[nt] - mean;
                    u[nt] = dd;
                    vs += dd * dd;
                }
                #pragma unroll
                for (int off = 8; off > 0; off >>= 1) vs += __shfl_xor(vs, off, 64);
                float rstd = rsqrtf(vs * (1.f / 96.f) + 1e-5f);
                #pragma unroll
                for (int nt = 0; nt < NT; nt++) {
                    int c = nt * 16 + l16;
                    out2[(size_t)r * N + c] = (bf16_t)(u[nt] * rstd * gv[nt] + bb[nt]);
                }
            }
    }
}

// ------------------------------------------------------------------
// Fused MLP v3b: out = x2 + fc2(gelu(fc1(h2)+b1))+b2  (t1 never in HBM)
// BM=128, 4 waves x 32 rows, one barrier/chunk (Tb wave-private),
// 4 blocks/CU, 3-term A&S erf GELU (R12), Tb stride 44 (R7).
// R11 PMC: VALU-bound (GELU ~24us of 58); conflicts 2.65M are NOT
// Tb (R7 removed exactly 32/chunk; remaining 256/chunk elsewhere,
// ~4us total — not the lever).
// ------------------------------------------------------------------
__global__ __launch_bounds__(256, 4)
void mlp_fused(const bf16_t* __restrict__ A, const bf16_t* __restrict__ W1g,
               const bf16_t* __restrict__ W2g, const float* __restrict__ b1,
               const float* __restrict__ b2, const float* __restrict__ resid,
               float* __restrict__ out)
{
    constexpr int KP1 = 104;   // 96+8
    constexpr int TBS = 44;    // Tb row stride
    __shared__ __attribute__((aligned(16))) bf16_t W1c[2][32 * KP1]; // 2x6656 B
    __shared__ __attribute__((aligned(16))) bf16_t W2c[2][96 * 40];  // 2x7680 B
    __shared__ __attribute__((aligned(16))) bf16_t Tb[128 * TBS];    // 11264 B

    const int tid = threadIdx.x;
    const int wave = tid >> 6, lane = tid & 63;
    const int quad = lane >> 4, l16 = lane & 15;
    const int m0 = blockIdx.x * 128;

    // A rows resident (full K=96): wave handles 32 rows (2 m-tiles)
    const bf16_t* Ar = A + (size_t)(m0 + wave * 32 + l16) * 96 + quad * 8;
    bf16x8 af[2][3];
    #pragma unroll
    for (int i = 0; i < 2; i++)
        #pragma unroll
        for (int kk = 0; kk < 3; kk++)
            af[i][kk] = *(const bf16x8*)(Ar + (size_t)i * 16 * 96 + kk * 32);

    // prefetch chunk 0 of W1 (32x96) and W2 (96 x cols 0..32) to regs
    bf16x4 w1n[3], w2n[3];
    #pragma unroll
    for (int q = 0; q < 3; q++) {
        int e = q * 256 + tid;
        w1n[q] = *(const bf16x4*)(W1g + e * 4);                       // rows 0..32 contiguous
        int row = e >> 3, sub = e & 7;
        w2n[q] = *(const bf16x4*)(W2g + row * 384 + sub * 4);
    }
    #pragma unroll
    for (int q = 0; q < 3; q++) {
        int e = q * 256 + tid;
        int r1 = e / 24, s1 = e - r1 * 24;
        *(bf16x4*)(&W1c[0][r1 * KP1 + s1 * 4]) = w1n[q];
        int row = e >> 3, sub = e & 7;
        *(bf16x4*)(&W2c[0][row * 40 + sub * 4]) = w2n[q];
    }
    __syncthreads();

    f32x4 acc2[2][6];
    #pragma unroll
    for (int i = 0; i < 2; i++)
        #pragma unroll
        for (int j = 0; j < 6; j++) { f32x4 zz = {0.f, 0.f, 0.f, 0.f}; acc2[i][j] = zz; }

    for (int c = 0; c < 12; c++) {
        const int pb = c & 1;
        // prefetch chunk c+1 to regs (vmcnt hidden by fc1 MFMAs + GELU)
        if (c < 11) {
            #pragma unroll
            for (int q = 0; q < 3; q++) {
                int e = q * 256 + tid;
                w1n[q] = *(const bf16x4*)(W1g + (c + 1) * 3072 + e * 4);
                int row = e >> 3, sub = e & 7;
                w2n[q] = *(const bf16x4*)(W2g + row * 384 + (c + 1) * 32 + sub * 4);
            }
        }
        // fc1 chunk: cols c*32..+32  (12 MFMA/wave), reads W1c[pb]
        f32x4 a1[2][2];
        #pragma unroll
        for (int i = 0; i < 2; i++)
            #pragma unroll
            for (int s = 0; s < 2; s++) { f32x4 zz = {0.f, 0.f, 0.f, 0.f}; a1[i][s] = zz; }
        #pragma unroll
        for (int s = 0; s < 2; s++) {
            int n = s * 16 + l16;
            #pragma unroll
            for (int kk = 0; kk < 3; kk++) {
                bf16x8 b = *(const bf16x8*)(&W1c[pb][n * KP1 + kk * 32 + quad * 8]);
                #pragma unroll
                for (int i = 0; i < 2; i++)
                    a1[i][s] = __builtin_amdgcn_mfma_f32_16x16x32_bf16(af[i][kk], b, a1[i][s], 0, 0, 0);
            }
        }
        // GELU -> Tb (wave-private rows; no barrier needed before fc2)
        #pragma unroll
        for (int s = 0; s < 2; s++) {
            int n = c * 32 + s * 16 + l16;
            float bv = b1[n];
            #pragma unroll
            for (int i = 0; i < 2; i++)
                #pragma unroll
                for (int ri = 0; ri < 4; ri++) {
                    float u = gelu_f(a1[i][s][ri] + bv);
                    Tb[(wave * 32 + i * 16 + quad * 4 + ri) * TBS + s * 16 + l16] = (bf16_t)u;
                }
        }
        // stage chunk c+1 into buffer pb^1 (its last readers finished
        // before barrier c-1 -> safe with the single end-of-chunk barrier)
        if (c < 11) {
            #pragma unroll
            for (int q = 0; q < 3; q++) {
                int e = q * 256 + tid;
                int r1 = e / 24, s1 = e - r1 * 24;
                *(bf16x4*)(&W1c[pb ^ 1][r1 * KP1 + s1 * 4]) = w1n[q];
                int row = e >> 3, sub = e & 7;
                *(bf16x4*)(&W2c[pb ^ 1][row * 40 + sub * 4]) = w2n[q];
            }
        }
        // fc2 partial (K=32): 12 MFMA/wave, reads own Tb rows + W2c[pb]
        bf16x8 a2[2];
        #pragma unroll
        for (int i = 0; i < 2; i++) {
            const bf16_t* tp = Tb + (wave * 32 + i * 16 + l16) * TBS + quad * 8;
            bf16x4 lo = *(const bf16x4*)tp;
            bf16x4 hi = *(const bf16x4*)(tp + 4);
            #pragma unroll
            for (int j = 0; j < 4; j++) { a2[i][j] = lo[j]; a2[i][j + 4] = hi[j]; }
        }
        #pragma unroll
        for (int nt = 0; nt < 6; nt++) {
            bf16x8 b = *(const bf16x8*)(&W2c[pb][(nt * 16 + l16) * 40 + quad * 8]);
            #pragma unroll
            for (int i = 0; i < 2; i++)
                acc2[i][nt] = __builtin_amdgcn_mfma_f32_16x16x32_bf16(a2[i], b, acc2[i][nt], 0, 0, 0);
        }
        __syncthreads();   // one barrier per chunk
    }

    // epilogue: + b2 + resid -> f32 out
    #pragma unroll
    for (int i = 0; i < 2; i++)
        #pragma unroll
        for (int nt = 0; nt < 6; nt++)
            #pragma unroll
            for (int ri = 0; ri < 4; ri++) {
                int r = m0 + wave * 32 + i * 16 + quad * 4 + ri;
                int cc = nt * 16 + l16;
                out[(size_t)r * 96 + cc] = acc2[i][nt][ri] + b2[cc] + resid[(size_t)r * 96 + cc];
            }
}

// ------------------------------------------------------------------
extern "C" void kernel_launch(void* const* d_in, const int* in_sizes, int n_in,
                              void* d_out, int out_size, void* d_ws, size_t ws_size,
                              hipStream_t stream)
{
    const float* x      = (const float*)d_in[0];
    const float* ln1_g  = (const float*)d_in[2];
    const float* ln1_b  = (const float*)d_in[3];
    const float* qkv_w  = (const float*)d_in[4];
    const float* qkv_b  = (const float*)d_in[5];
    const float* proj_w = (const float*)d_in[6];
    const float* proj_b = (const float*)d_in[7];
    const float* ln2_g  = (const float*)d_in[8];
    const float* ln2_b  = (const float*)d_in[9];
    const float* fc1_w  = (const float*)d_in[10];
    const float* fc1_b  = (const float*)d_in[11];
    const float* fc2_w  = (const float*)d_in[12];
    const float* fc2_b  = (const float*)d_in[13];

    // ---- workspace 170.1 MB (aliased by liveness) ----
    const size_t SZ_WB = 110592ull * 2;
    const size_t SZ_HP = 10616832ull * 2;
    const size_t SZ_Y  = 31850496ull * 2;
    const size_t SZ_YV = 10616832ull * 2;

    char* ws = (char*)d_ws;
    size_t oWB = 0;
    size_t oHP = oWB + SZ_WB;
    size_t oY  = oHP + SZ_HP;
    size_t oYV = oY + SZ_Y;
    size_t oS  = oYV + SZ_YV;

    bf16_t* Wb    = (bf16_t*)(ws + oWB);
    bf16_t* Wqkv  = Wb;
    bf16_t* Wproj = Wb + 27648;
    bf16_t* Wfc1  = Wb + 36864;
    bf16_t* Wfc2  = Wb + 73728;
    bf16_t* hp    = (bf16_t*)(ws + oHP);   // o_rows / h2
    bf16_t* Y     = (bf16_t*)(ws + oY);    // q,k; V goes straight to Yv
    bf16_t* Yv    = (bf16_t*)(ws + oYV);
    bf16_t* Pb    = (bf16_t*)(ws + oY);    // P aliases Y
    bf16_t* Sb    = (bf16_t*)(ws + oS);    // S bf16
    float*  x2    = (float*)(ws + oS);     // x2 aliases S
    float*  outp  = (float*)d_out;

    dim3 blk(256);

    // 1. weights -> bf16
    conv_w<<<dim3(432), blk, 0, stream>>>(qkv_w, proj_w, fc1_w, fc2_w, Wb);
    // 2. QKV gemm with FUSED LN1+permute -> Y (q,k) + Yv (V transposed)
    qkv_fused<<<dim3(432), blk, 0, stream>>>(x, Wqkv, Y, qkv_b, Yv, ln1_g, ln1_b);
    // 3. S = Q@K^T -> bf16
    gemm_bt<128, 1, 18><<<dim3(328, 1, 3), blk, 0, stream>>>(Y, Y + 3 * YSTR, Sb,
                                                             1536, YSTR, YSTR, SSTR, SCALE_Q);
    // 4. softmax (wave/row, vectorized) -> P
    softmax_k<<<dim3(576, 1, 3), blk, 0, stream>>>(Sb, Pb, SSTR, SSTR);
    // 5. O = P@V^T -> o_rows in hp
    gemm_bt<128, 2, 12><<<dim3(216, 1, 3), blk, 0, stream>>>(Pb, Yv, hp,
                                                             2304, SSTR, YSTR, 0, 0.f);
    // 6. proj + residual -> x2 (f32) + fused LN2 -> h2 (hp)
    gemm_ws<96, 96, 96, 5><<<dim3(432), blk, 0, stream>>>(hp, Wproj, x2, proj_b, x,
                                                          hp, ln2_g, ln2_b);
    // 7. fused MLP v3b (fc1+GELU+fc2+residual) -> out
    mlp_fused<<<dim3(864), blk, 0, stream>>>(hp, Wfc1, Wfc2, fc1_b, fc2_b, x2, outp);
}